// Round 7
// baseline (176.162 us; speedup 1.0000x reference)
//
#include <hip/hip_runtime.h>
#include <math.h>

// Problem constants (B=4, N=2048, D=1024, DL=64, DK=128, DC=8)

// Workspace layout (float offsets). ws is poisoned 0xAA before EVERY launch.
// Protocol: inter-phase data is WRITTEN via relaxed agent-scope atomic stores
// (sc1 -> coherence point, bypassing non-coherent per-XCD L2) and READ via
// normal cached loads, where each block's FIRST normal touch of a line happens
// strictly after the producing counter is observed. Kernel-dispatch boundary
// invalidates L2s (stale poison can't survive into this launch's reads).
constexpr int XBAR_OFF = 0;       // B*1024   = 4096
constexpr int CTRL_OFF = 4096;    // 512 int slots reserved
constexpr int SC_OFF   = 4608;    // B*16     = 64   [inv_tau, screen, czq0..7]
constexpr int QS_OFF   = 4672;    // B*128    = 512
constexpr int US_OFF   = 5184;    // B*8*128  = 4096
constexpr int AV_OFF   = 9280;    // B*9*1024 = 36864
constexpr int WZ_OFF   = 46144;   // B*N*8    = 65536
constexpr int DIST_OFF = 111680;  // B*N      = 8192
constexpr int S_OFF    = 119872;  // B*N      = 8192
constexpr int Y_OFF    = 128064;  // B*128    = 512
constexpr int PART_OFF = 128576;  // B*64*1024= 262144  P4 partial sums
constexpr int WS_FLOATS = 390720;

constexpr int NBLK = 256;
constexpr int MAGIC = 0x1F2E3D4C;
// ctrl counters, one per 128B line:
constexpr int C_MAGIC = 0;
constexpr int C_Q  = 32 * 1;  // target 32
constexpr int C_WZ = 32 * 2;  // target 32
constexpr int C_SC = 32 * 3;  // target 1
constexpr int C_U  = 32 * 4;  // target 64
constexpr int C_AV = 32 * 5;  // target 64
constexpr int C_S3 = 32 * 6;  // target 256
constexpr int C_P4 = 32 * 7;  // target 256
constexpr int C_P5 = 32 * 8;  // target 256
constexpr int C_Y  = 32 * 9;  // target 256
constexpr int CTRL_INTS = 32 * 10;

__device__ __forceinline__ float wave_sum(float v) {
#pragma unroll
  for (int off = 32; off > 0; off >>= 1) v += __shfl_xor(v, off, 64);
  return v;
}

// Publish to the coherence point (bypasses non-coherent L2).
__device__ __forceinline__ void pub(float* p, float v) {
  __hip_atomic_store(p, v, __ATOMIC_RELAXED, __HIP_MEMORY_SCOPE_AGENT);
}
__device__ __forceinline__ void pub2(float* p, float a, float b) {
  union { float f[2]; unsigned long long u; } v;
  v.f[0] = a; v.f[1] = b;
  __hip_atomic_store((unsigned long long*)p, v.u, __ATOMIC_RELAXED,
                     __HIP_MEMORY_SCOPE_AGENT);
}

// Producer signal: __syncthreads drains all waves' outstanding (sc1) stores
// before s_barrier (measured codegen), so the counter bump publishes "done".
__device__ __forceinline__ void sig(int* c) {
  __syncthreads();
  if (threadIdx.x == 0)
    __hip_atomic_fetch_add(c, 1, __ATOMIC_RELAXED, __HIP_MEMORY_SCOPE_AGENT);
}
// Consumer wait: load-only spin (no RMW storm), then block-wide release.
__device__ __forceinline__ void wait_ge(int* c, int t) {
  if (threadIdx.x == 0)
    while (__hip_atomic_load(c, __ATOMIC_RELAXED,
                             __HIP_MEMORY_SCOPE_AGENT) < t)
      __builtin_amdgcn_s_sleep(1);
  __syncthreads();
}

// ---------------------------------------------------------------------------
// Single persistent kernel, 256 blocks (1/CU), producer-consumer dataflow:
//  A: q(32) | wz/dist(32) | scalars(1)
//  B: u (blocks 0..63, waits C_Q)
//  C: av (blocks 64..127, waits C_U,C_SC)
//  D: scores (all, waits C_AV,C_WZ,C_SC)
//  E: softmax + partial weighted x-sums (all, waits C_S3)
//  F: reduce partials -> xbar (all, waits C_P4)
//  G: y = WV xbar (all, waits C_P5)
//  H: out = WO y (all, waits C_Y)
// ---------------------------------------------------------------------------
__global__ __launch_bounds__(256) void k_fused(
    const float* __restrict__ xq, const float* __restrict__ zq,
    const float* __restrict__ x_keys, const float* __restrict__ z_keys,
    const float* __restrict__ WQ, const float* __restrict__ WQz,
    const float* __restrict__ G, const float* __restrict__ WK,
    const float* __restrict__ WV, const float* __restrict__ WO,
    const float* __restrict__ Wd, const float* __restrict__ bb,
    const float* __restrict__ be, const float* __restrict__ bo,
    const float* __restrict__ lsig, float* __restrict__ ws,
    float* __restrict__ out) {
  __shared__ __align__(16) float shm[9824];
  const int tid = threadIdx.x;
  const int blk = blockIdx.x;
  int* ctrl = (int*)(ws + CTRL_OFF);

  // ---- ctrl init (block 0), then everyone gates on MAGIC ----
  if (blk == 0) {
    for (int i = tid; i < CTRL_INTS; i += 256)
      __hip_atomic_store(ctrl + i, (i == C_MAGIC) ? 0 : 0, __ATOMIC_RELAXED,
                         __HIP_MEMORY_SCOPE_AGENT);
    __syncthreads();
    if (tid == 0)
      __hip_atomic_store(ctrl + C_MAGIC, MAGIC, __ATOMIC_RELAXED,
                         __HIP_MEMORY_SCOPE_AGENT);
  }
  if (tid == 0)
    while (__hip_atomic_load(ctrl + C_MAGIC, __ATOMIC_RELAXED,
                             __HIP_MEMORY_SCOPE_AGENT) != MAGIC)
      __builtin_amdgcn_s_sleep(1);
  __syncthreads();

  // ========================= Stage A =========================
  if (blk < 32) {
    // q[b,a] = WQ[a].xq[b] + WQz[a].zq[b] + sum_ij G[a,i,j] zq_i zq_j
    float* xqs = shm;           // 1024
    float* zqs = shm + 1024;    // 64
    float* part = shm + 1088;   // 256
    const int b = blk >> 3, as_ = blk & 7;
    for (int i = tid; i < 1024; i += 256) xqs[i] = xq[b * 1024 + i];
    if (tid < 64) zqs[tid] = zq[b * 64 + tid];
    __syncthreads();
    const int seg = tid & 15;
    const int a = as_ * 16 + (tid >> 4);
    const float4* wq4 = (const float4*)(WQ + a * 1024 + seg * 64);
    const float4* xs4 = (const float4*)(xqs + seg * 64);
    float p = 0;
#pragma unroll
    for (int c = 0; c < 16; ++c) {
      float4 w = wq4[c], x = xs4[c];
      p += w.x * x.x + w.y * x.y + w.z * x.z + w.w * x.w;
    }
#pragma unroll
    for (int c = 0; c < 4; ++c)
      p += WQz[a * 64 + seg * 4 + c] * zqs[seg * 4 + c];
#pragma unroll
    for (int ii = 0; ii < 4; ++ii) {
      const int i = seg * 4 + ii;
      const float4* g4 = (const float4*)(G + a * 4096 + i * 64);
      float inner = 0;
#pragma unroll
      for (int c = 0; c < 16; ++c) {
        float4 gv = g4[c];
        const float4 zv = *(const float4*)(zqs + c * 4);
        inner += gv.x * zv.x + gv.y * zv.y + gv.z * zv.z + gv.w * zv.w;
      }
      p += zqs[i] * inner;
    }
    part[tid] = p;
    __syncthreads();
    if (tid < 16) {
      float s = 0;
#pragma unroll
      for (int h = 0; h < 16; ++h) s += part[tid * 16 + h];
      pub(&ws[QS_OFF + b * 128 + as_ * 16 + tid], s);
    }
    sig(ctrl + C_Q);
  } else if (blk < 64) {
    // per-position: wz[r] = Wd[r].z_k ; dist = |zq - zk|^2
    float* sWd = shm;          // 512
    float* zqs = shm + 512;    // 256
    sWd[tid] = Wd[tid];
    sWd[256 + tid] = Wd[256 + tid];
    zqs[tid] = zq[tid];
    __syncthreads();
    const int bn = (blk - 32) * 256 + tid;
    const int b = bn >> 11;
    const float4* zk4 = (const float4*)(z_keys + (size_t)bn * 64);
    const float* zqb = zqs + b * 64;
    float wzv[8] = {0, 0, 0, 0, 0, 0, 0, 0};
    float dist = 0;
    for (int l4 = 0; l4 < 16; ++l4) {
      float4 z4 = zk4[l4];
      float ze[4] = {z4.x, z4.y, z4.z, z4.w};
#pragma unroll
      for (int e = 0; e < 4; ++e) {
        const int l = l4 * 4 + e;
        float z = ze[e];
        float dz = zqb[l] - z;
        dist += dz * dz;
#pragma unroll
        for (int r = 0; r < 8; ++r) wzv[r] += sWd[r * 64 + l] * z;
      }
    }
#pragma unroll
    for (int r = 0; r < 8; ++r) pub(&ws[WZ_OFF + bn * 8 + r], wzv[r]);
    pub(&ws[DIST_OFF + bn], dist);
    sig(ctrl + C_WZ);
  } else if (blk == 64) {
    float* zqs = shm;
    zqs[tid] = zq[tid];
    __syncthreads();
    const int b = tid >> 6, l = tid & 63;
    float z = zqs[b * 64 + l];
    float r2 = wave_sum(z * z);
    float cz[8];
#pragma unroll
    for (int r = 0; r < 8; ++r) cz[r] = wave_sum(Wd[r * 64 + l] * z);
    if (l == 0) {
      r2 = fminf(r2, 1.0f - 1e-6f);
      float lam = 2.0f / (1.0f - r2 + 1e-6f);
      pub(&ws[SC_OFF + b * 16 + 0], lam / sqrtf(128.0f));            // 1/tau
      pub(&ws[SC_OFF + b * 16 + 1], expf(lsig[0]) * 0.5f * lam * lam);
#pragma unroll
      for (int r = 0; r < 8; ++r) pub(&ws[SC_OFF + b * 16 + 2 + r], cz[r]);
    }
    sig(ctrl + C_SC);
  }

  // ========================= Stage B: u =========================
  if (blk < 64) {
    wait_ge(ctrl + C_Q, 32);
    const int r = blk >> 3, jc = blk & 7;
    float* sq = shm;          // 512
    float* red = shm + 512;   // 1024
    for (int o = tid; o < 512; o += 256) sq[o] = ws[QS_OFF + o];
    __syncthreads();
    const int jl = tid & 15, is = tid >> 4;
    const int j = jc * 16 + jl;
    float acc[4] = {0, 0, 0, 0};
    const float* arrs[3] = {bb, be, bo};
    const float wgt[3] = {1.0f, 0.5f, 0.3f};
#pragma unroll
    for (int arr = 0; arr < 3; ++arr) {
      const float w = wgt[arr];
      const float* base = arrs[arr] + r * 16384;
#pragma unroll
      for (int k = 0; k < 8; ++k) {
        const int i = is * 8 + k;
        const float sk = w * (base[i * 128 + j] - base[j * 128 + i]);
#pragma unroll
        for (int b = 0; b < 4; ++b) acc[b] += sk * sq[b * 128 + i];
      }
    }
#pragma unroll
    for (int b = 0; b < 4; ++b) red[(jl * 4 + b) * 16 + is] = acc[b];
    __syncthreads();
    if (tid < 64) {
      const int jl2 = tid >> 2, b = tid & 3;
      float s = 0;
#pragma unroll
      for (int is2 = 0; is2 < 16; ++is2) s += red[(jl2 * 4 + b) * 16 + is2];
      pub(&ws[US_OFF + b * 1024 + r * 128 + jc * 16 + jl2], s);
    }
    sig(ctrl + C_U);
  }

  // ========================= Stage C: av =========================
  if (blk >= 64 && blk < 128) {
    wait_ge(ctrl + C_U, 64);
    wait_ge(ctrl + C_SC, 1);
    const int lb = blk - 64;
    const int b = lb >> 4, dbase = (lb & 15) * 64;
    float* qu = shm;            // 1152
    float* part = shm + 1152;   // 2304
    float* fin = shm + 3456;    // 576
    float* czq = shm + 4032;    // 8
    for (int o = tid; o < 1152; o += 256)
      qu[o] = (o < 128) ? ws[QS_OFF + b * 128 + o]
                        : ws[US_OFF + b * 1024 + (o - 128)];
    if (tid < 8) czq[tid] = ws[SC_OFF + b * 16 + 2 + tid];
    __syncthreads();
    const int kq = tid >> 6, dloc = tid & 63;
    float acc[9];
#pragma unroll
    for (int jj = 0; jj < 9; ++jj) acc[jj] = 0;
    const float* wkp = WK + dbase + dloc;
#pragma unroll 4
    for (int k = kq * 32; k < kq * 32 + 32; ++k) {
      const float wk = wkp[k * 1024];
#pragma unroll
      for (int jj = 0; jj < 9; ++jj) acc[jj] += qu[jj * 128 + k] * wk;
    }
#pragma unroll
    for (int jj = 0; jj < 9; ++jj) part[kq * 576 + jj * 64 + dloc] = acc[jj];
    __syncthreads();
    for (int o = tid; o < 576; o += 256)
      fin[o] = part[o] + part[576 + o] + part[1152 + o] + part[1728 + o];
    __syncthreads();
    float* av = ws + AV_OFF + b * 9216;
    for (int o = tid; o < 576; o += 256) {
      const int jj = o >> 6, dl = o & 63;
      float val = fin[o];
      if (jj == 0) {
#pragma unroll
        for (int rr = 0; rr < 8; ++rr)
          val += czq[rr] * fin[(1 + rr) * 64 + dl];
      }
      pub(&av[jj * 1024 + dbase + dl], val);
    }
    sig(ctrl + C_AV);
  }

  // ========================= Stage D: scores =========================
  {
    wait_ge(ctrl + C_AV, 64);
    wait_ge(ctrl + C_WZ, 32);
    wait_ge(ctrl + C_SC, 1);
    float* sav = shm;  // 9216 (+inv_tau at [9216])
    const int b = blk >> 6;
    const float* avg = ws + AV_OFF + b * 9216;
    for (int i = tid * 4; i < 9216; i += 1024)
      *(float4*)(sav + i) = *(const float4*)(avg + i);
    if (tid == 0) shm[9216] = ws[SC_OFF + b * 16];  // inv_tau
    __syncthreads();

    const int wave = tid >> 6, lane = tid & 63;
    for (int half = 0; half < 2; ++half) {
      const int nbase = (blk & 63) * 32 + half * 16 + wave * 4;
      const float* xb = x_keys + ((size_t)(b * 2048 + nbase)) * 1024;

      float acc[9][4];
#pragma unroll
      for (int j = 0; j < 9; ++j)
#pragma unroll
        for (int p = 0; p < 4; ++p) acc[j][p] = 0;

#pragma unroll
      for (int c = 0; c < 4; ++c) {
        const int off = c * 256 + lane * 4;
        float4 xv[4];
#pragma unroll
        for (int p = 0; p < 4; ++p)
          xv[p] = *(const float4*)(xb + p * 1024 + off);
#pragma unroll
        for (int j = 0; j < 9; ++j) {
          float4 a = *(const float4*)(sav + j * 1024 + off);
#pragma unroll
          for (int p = 0; p < 4; ++p)
            acc[j][p] +=
                a.x * xv[p].x + a.y * xv[p].y + a.z * xv[p].z + a.w * xv[p].w;
        }
      }
#pragma unroll
      for (int j = 0; j < 9; ++j)
#pragma unroll
        for (int p = 0; p < 4; ++p) acc[j][p] = wave_sum(acc[j][p]);

      if (lane == 0) {
        const float it = shm[9216];
        for (int p = 0; p < 4; ++p) {
          const int bn = b * 2048 + nbase + p;
          const float* wz = ws + WZ_OFF + bn * 8;
          float s = acc[0][p];
#pragma unroll
          for (int r = 0; r < 8; ++r) s -= wz[r] * acc[1 + r][p];
          pub(&ws[S_OFF + bn], s * it);
        }
      }
    }
    sig(ctrl + C_S3);
  }

  // ========== Stage E: softmax + partial weighted x-sum (per 32-n tile) =====
  {
    wait_ge(ctrl + C_S3, 256);
    const int b = blk >> 6, nt = blk & 63, n0 = nt * 32;
    float* red = shm;        // 256
    float* sw = shm + 256;   // 32
    float sv[8];
    float vmax = -1e30f;
#pragma unroll
    for (int i = 0; i < 8; ++i) {
      sv[i] = ws[S_OFF + b * 2048 + i * 256 + tid];
      vmax = fmaxf(vmax, sv[i]);
    }
    red[tid] = vmax;
    __syncthreads();
    for (int s = 128; s > 0; s >>= 1) {
      if (tid < s) red[tid] = fmaxf(red[tid], red[tid + s]);
      __syncthreads();
    }
    const float m = red[0];
    __syncthreads();
    float lsum = 0;
#pragma unroll
    for (int i = 0; i < 8; ++i) lsum += expf(sv[i] - m);
    red[tid] = lsum;
    __syncthreads();
    for (int s = 128; s > 0; s >>= 1) {
      if (tid < s) red[tid] += red[tid + s];
      __syncthreads();
    }
    const float rl = 1.0f / red[0];
    const float screen = ws[SC_OFF + b * 16 + 1];
    if (tid < 32) {
      const int n = n0 + tid;
      sw[tid] = expf(ws[S_OFF + b * 2048 + n] - m -
                     screen * ws[DIST_OFF + b * 2048 + n]) * rl;
    }
    __syncthreads();
    // weighted sum over 32 rows; thread owns 4 consecutive d (float4 loads)
    const float4* xb4 =
        (const float4*)(x_keys + ((size_t)(b * 2048 + n0)) * 1024);
    float4 acc = {0, 0, 0, 0};
#pragma unroll 4
    for (int n = 0; n < 32; ++n) {
      const float w = sw[n];
      float4 x = xb4[n * 256 + tid];
      acc.x += w * x.x; acc.y += w * x.y;
      acc.z += w * x.z; acc.w += w * x.w;
    }
    float* pw = ws + PART_OFF + ((b * 64 + nt) << 10) + tid * 4;
    pub2(pw, acc.x, acc.y);
    pub2(pw + 2, acc.z, acc.w);
    sig(ctrl + C_P4);
  }

  // ========== Stage F: reduce partials -> xbar ==========
  {
    wait_ge(ctrl + C_P4, 256);
    const int b = blk >> 6, d0 = (blk & 63) * 16;
    const int nt = tid >> 2, q = tid & 3;
    float4 v = *(const float4*)(ws + PART_OFF + ((b * 64 + nt) << 10) + d0 +
                                q * 4);
    float4* shm4 = (float4*)shm;
    shm4[tid] = v;
    __syncthreads();
    for (int s = 32; s > 0; s >>= 1) {
      if (nt < s) {
        float4 a = shm4[tid], c = shm4[tid + s * 4];
        a.x += c.x; a.y += c.y; a.z += c.z; a.w += c.w;
        shm4[tid] = a;
      }
      __syncthreads();
    }
    if (tid < 4) {
      float4 a = shm4[tid];
      float* p = ws + XBAR_OFF + b * 1024 + d0 + tid * 4;
      pub2(p, a.x, a.y);
      pub2(p + 2, a.z, a.w);
    }
    sig(ctrl + C_P5);
  }

  // ========== Stage G: y = WV xbar (one (b,dk) per block-slot) ==========
  {
    wait_ge(ctrl + C_P5, 256);
    for (int t = blk; t < 512; t += 256) {
      const int b = t >> 7, dk = t & 127;
      const float4* wv4 = (const float4*)(WV + dk * 1024);
      const float4* xb4 = (const float4*)(ws + XBAR_OFF + b * 1024);
      float4 w = wv4[tid], x = xb4[tid];
      float p = w.x * x.x + w.y * x.y + w.z * x.z + w.w * x.w;
      p = wave_sum(p);
      if ((tid & 63) == 0) shm[tid >> 6] = p;
      __syncthreads();
      if (tid == 0)
        pub(&ws[Y_OFF + b * 128 + dk], shm[0] + shm[1] + shm[2] + shm[3]);
      __syncthreads();
    }
    sig(ctrl + C_Y);
  }

  // ========== Stage H: out = WO y ==========
  {
    wait_ge(ctrl + C_Y, 256);
    const int b = blk >> 6, d0 = (blk & 63) * 16;
    float* sy = shm;           // 128
    float* part = shm + 128;   // 256
    if (tid < 128) sy[tid] = ws[Y_OFF + b * 128 + tid];
    __syncthreads();
    const int dloc = tid >> 4, seg = tid & 15;
    const float4* wo4 = (const float4*)(WO + (d0 + dloc) * 128 + seg * 8);
    const float4* sy4 = (const float4*)(sy + seg * 8);
    float4 w0 = wo4[0], w1 = wo4[1], y0 = sy4[0], y1 = sy4[1];
    float p = w0.x * y0.x + w0.y * y0.y + w0.z * y0.z + w0.w * y0.w +
              w1.x * y1.x + w1.y * y1.y + w1.z * y1.z + w1.w * y1.w;
    part[tid] = p;
    __syncthreads();
    if (tid < 16) {
      float s = 0;
#pragma unroll
      for (int h = 0; h < 16; ++h) s += part[tid * 16 + h];
      out[b * 1024 + d0 + tid] = s;
    }
  }
}

// ---------------------------------------------------------------------------
extern "C" void kernel_launch(void* const* d_in, const int* in_sizes, int n_in,
                              void* d_out, int out_size, void* d_ws,
                              size_t ws_size, hipStream_t stream) {
  const float* xq  = (const float*)d_in[0];
  const float* zq  = (const float*)d_in[1];
  const float* xk  = (const float*)d_in[2];
  const float* zk  = (const float*)d_in[3];
  const float* WQ  = (const float*)d_in[4];
  const float* WQz = (const float*)d_in[5];
  const float* G   = (const float*)d_in[6];
  const float* WK  = (const float*)d_in[7];
  const float* WV  = (const float*)d_in[8];
  const float* WO  = (const float*)d_in[9];
  const float* Wd  = (const float*)d_in[10];
  const float* bb  = (const float*)d_in[11];
  const float* be  = (const float*)d_in[12];
  const float* bo  = (const float*)d_in[13];
  const float* ls  = (const float*)d_in[14];
  float* ws  = (float*)d_ws;
  float* out = (float*)d_out;
  if (ws_size < (size_t)WS_FLOATS * sizeof(float)) return;

  hipLaunchKernelGGL(k_fused, dim3(NBLK), dim3(256), 0, stream,
                     xq, zq, xk, zk, WQ, WQz, G, WK, WV, WO, Wd, bb, be, bo,
                     ls, ws, out);
}